// Round 1
// baseline (3208.357 us; speedup 1.0000x reference)
//
#include <hip/hip_runtime.h>

// IBNModel: graph-coupled bidirectional GRU + decoder.
// B=16, H=64, N=512, C=3, E=128, D=32, L_OUT=12, LAYERS=2. All fp32.
//
// Structure:
//  K1 dynadj_kernel : A_f, A_b = softmax(relu(E1 @ E2^T)) row-wise.       (ws)
//  K2 msg_kernel    : msg[t,b,0:9,n] = [xt, xt@adj, xt@A_f] for all t;    (ws)
//                     msgb3[b,0:3,n] = xt(H-1)@A_b (backward-only part).
//  K3 rec_kernel    : per-(b,n)-column GRU for all 64 steps (columns are
//                     independent once msg is precomputed!), fused backward
//                     step (c0=0 => no matvec) + decoder epilogue.

#define NB 512
#define EB 128

__device__ __forceinline__ float sigmoidf_(float x) { return 1.f / (1.f + __expf(-x)); }
__device__ __forceinline__ float tanhf_(float x) { return 1.f - 2.f / (__expf(2.f * x) + 1.f); }

// ---------------- K1: dynamic adjacency (softmax(relu(E1 E2^T))) ----------
__global__ __launch_bounds__(256) void dynadj_kernel(
    const float* __restrict__ E1f, const float* __restrict__ E2f,
    const float* __restrict__ E1b, const float* __restrict__ E2b,
    float* __restrict__ Af, float* __restrict__ Ab) {
  int bid = blockIdx.x;           // 0..1023 : [which][row]
  int which = bid >> 9;
  int row = bid & 511;
  const float* E1 = which ? E1b : E1f;
  const float* E2 = which ? E2b : E2f;
  float* A = which ? Ab : Af;
  __shared__ float e1[32];
  __shared__ float red[256];
  int tid = threadIdx.x;
  if (tid < 32) e1[tid] = E1[row * 32 + tid];
  __syncthreads();
  float s[2];
#pragma unroll
  for (int h = 0; h < 2; ++h) {
    int m = tid + h * 256;
    const float4* e2 = (const float4*)(E2 + m * 32);
    float acc = 0.f;
#pragma unroll
    for (int d4 = 0; d4 < 8; ++d4) {
      float4 v = e2[d4];
      acc = fmaf(v.x, e1[d4 * 4 + 0], acc);
      acc = fmaf(v.y, e1[d4 * 4 + 1], acc);
      acc = fmaf(v.z, e1[d4 * 4 + 2], acc);
      acc = fmaf(v.w, e1[d4 * 4 + 3], acc);
    }
    s[h] = fmaxf(acc, 0.f);      // relu
  }
  red[tid] = fmaxf(s[0], s[1]);
  __syncthreads();
  for (int off = 128; off > 0; off >>= 1) {
    if (tid < off) red[tid] = fmaxf(red[tid], red[tid + off]);
    __syncthreads();
  }
  float mx = red[0];
  __syncthreads();
  float e0 = __expf(s[0] - mx), e1v = __expf(s[1] - mx);
  red[tid] = e0 + e1v;
  __syncthreads();
  for (int off = 128; off > 0; off >>= 1) {
    if (tid < off) red[tid] += red[tid + off];
    __syncthreads();
  }
  float inv = 1.f / red[0];
  A[row * 512 + tid] = e0 * inv;
  A[row * 512 + tid + 256] = e1v * inv;
}

// ---------------- K2: message precompute --------------------------------
// msg layout: msg[((t*16+b)*9 + ch)*512 + n]
__global__ __launch_bounds__(256) void msg_kernel(
    const float* __restrict__ x, const float* __restrict__ adj,
    const float* __restrict__ Af, const float* __restrict__ Ab,
    float* __restrict__ msg, float* __restrict__ msgb3) {
  int bid = blockIdx.x;
  __shared__ float xls[3 * 512];
  int tid = threadIdx.x;
  int t, b;
  bool back;
  if (bid < 1024) { t = bid >> 4; b = bid & 15; back = false; }
  else            { t = 63; b = bid - 1024; back = true; }
  // x_input[b][t][n][c] contiguous over (n,c) for fixed (b,t)
  const float* xp = x + ((size_t)(b * 64 + t)) * 512 * 3;
#pragma unroll
  for (int i = 0; i < 6; ++i) {
    int j = tid + i * 256;
    float v = xp[j];
    int n = j / 3, c = j - n * 3;
    xls[c * 512 + n] = v;       // transpose to [c][n]
  }
  __syncthreads();
  const float* Ad = back ? Ab : Af;
  float accp[3][2] = {{0.f, 0.f}, {0.f, 0.f}, {0.f, 0.f}};
  float accd[3][2] = {{0.f, 0.f}, {0.f, 0.f}, {0.f, 0.f}};
  for (int n = 0; n < 512; ++n) {
    float x0 = xls[n], x1 = xls[512 + n], x2 = xls[1024 + n];
    float a0 = adj[n * 512 + tid], a1 = adj[n * 512 + tid + 256];
    float d0 = Ad[n * 512 + tid], d1 = Ad[n * 512 + tid + 256];
    accp[0][0] = fmaf(x0, a0, accp[0][0]);
    accp[1][0] = fmaf(x1, a0, accp[1][0]);
    accp[2][0] = fmaf(x2, a0, accp[2][0]);
    accp[0][1] = fmaf(x0, a1, accp[0][1]);
    accp[1][1] = fmaf(x1, a1, accp[1][1]);
    accp[2][1] = fmaf(x2, a1, accp[2][1]);
    accd[0][0] = fmaf(x0, d0, accd[0][0]);
    accd[1][0] = fmaf(x1, d0, accd[1][0]);
    accd[2][0] = fmaf(x2, d0, accd[2][0]);
    accd[0][1] = fmaf(x0, d1, accd[0][1]);
    accd[1][1] = fmaf(x1, d1, accd[1][1]);
    accd[2][1] = fmaf(x2, d1, accd[2][1]);
  }
  if (!back) {
    float* mp = msg + ((size_t)(t * 16 + b)) * 9 * 512;
#pragma unroll
    for (int h = 0; h < 2; ++h) {
      int m = tid + h * 256;
      mp[0 * 512 + m] = xls[m];
      mp[1 * 512 + m] = xls[512 + m];
      mp[2 * 512 + m] = xls[1024 + m];
      mp[3 * 512 + m] = accp[0][h];
      mp[4 * 512 + m] = accp[1][h];
      mp[5 * 512 + m] = accp[2][h];
      mp[6 * 512 + m] = accd[0][h];
      mp[7 * 512 + m] = accd[1][h];
      mp[8 * 512 + m] = accd[2][h];
    }
  } else {
    float* mp = msgb3 + (size_t)b * 3 * 512;
#pragma unroll
    for (int h = 0; h < 2; ++h) {
      int m = tid + h * 256;
      mp[0 * 512 + m] = accd[0][h];
      mp[1 * 512 + m] = accd[1][h];
      mp[2 * 512 + m] = accd[2][h];
    }
  }
}

// ---------------- K3: recurrence + backward + decoder --------------------
// 256 blocks (b in 0..15, n-tile of 32), 512 threads:
//   col = tid&31 (column within tile), og = tid>>5 (0..15), thread owns
//   output rows o = og*8 .. og*8+7 of every gate.
#define TILE 32
__global__ __launch_bounds__(512, 2) void rec_kernel(
    const float* __restrict__ msg, const float* __restrict__ msgb3,
    const float* __restrict__ Wf, const float* __restrict__ Uf,
    const float* __restrict__ bf, const float* __restrict__ Wb,
    const float* __restrict__ bb, const float* __restrict__ dec_w,
    const float* __restrict__ dec_b, const float* __restrict__ out_w,
    const float* __restrict__ out_b, float* __restrict__ out) {
  __shared__ float Wl[3 * 128 * 9];     // 3456
  __shared__ float bl[3 * 128];         // 384
  __shared__ float c_lds[128 * TILE];   // 4096 (state / h_fwd)
  __shared__ float rc_lds[128 * TILE];  // 4096 (r*c, then h_back)
  __shared__ float hdec[12 * TILE];     // 384
  int tid = threadIdx.x;
  int bid = blockIdx.x;
  int b = bid >> 4;
  int n0 = (bid & 15) * TILE;
  int col = tid & 31;
  int og = tid >> 5;
  int obase = og * 8;

  for (int i = tid; i < 3456; i += 512) Wl[i] = Wf[i];
  if (tid < 384) bl[tid] = bf[tid];
  for (int i = tid; i < 128 * TILE; i += 512) c_lds[i] = 0.f;
  __syncthreads();

  const float4* U0 = (const float4*)(Uf);              // [128][32] float4
  const float4* U1 = (const float4*)(Uf + 128 * 128);
  const float4* U2 = (const float4*)(Uf + 2 * 128 * 128);

  for (int t = 0; t < 64; ++t) {
    const float* mp = msg + ((size_t)(t * 16 + b)) * 9 * 512 + n0 + col;
    float mv[9];
#pragma unroll
    for (int j = 0; j < 9; ++j) mv[j] = mp[j * 512];
    float accr[8], accu[8], accg[8];
#pragma unroll
    for (int k = 0; k < 8; ++k) {
      int o = obase + k;
      float ar = bl[o], au = bl[128 + o], ag = bl[256 + o];
#pragma unroll
      for (int j = 0; j < 9; ++j) {
        ar = fmaf(Wl[o * 9 + j], mv[j], ar);
        au = fmaf(Wl[1152 + o * 9 + j], mv[j], au);
        ag = fmaf(Wl[2304 + o * 9 + j], mv[j], ag);
      }
      accr[k] = ar; accu[k] = au; accg[k] = ag;
    }
    // phase 1: r = sigmoid(gx_r + U0@c), also accumulate U1@c for u
    for (int e4 = 0; e4 < 32; ++e4) {
      int eb = e4 * 4;
      float c0 = c_lds[(eb + 0) * 32 + col];
      float c1 = c_lds[(eb + 1) * 32 + col];
      float c2 = c_lds[(eb + 2) * 32 + col];
      float c3 = c_lds[(eb + 3) * 32 + col];
#pragma unroll
      for (int k = 0; k < 8; ++k) {
        float4 a = U0[(obase + k) * 32 + e4];
        accr[k] = fmaf(a.w, c3, fmaf(a.z, c2, fmaf(a.y, c1, fmaf(a.x, c0, accr[k]))));
        float4 q = U1[(obase + k) * 32 + e4];
        accu[k] = fmaf(q.w, c3, fmaf(q.z, c2, fmaf(q.y, c1, fmaf(q.x, c0, accu[k]))));
      }
    }
#pragma unroll
    for (int k = 0; k < 8; ++k) {
      float r = sigmoidf_(accr[k]);
      rc_lds[(obase + k) * 32 + col] = r * c_lds[(obase + k) * 32 + col];
    }
    __syncthreads();   // rc visible; everyone's phase-1 c reads done
    // phase 2: g = tanh(gx_g + U2@(r*c))
    for (int e4 = 0; e4 < 32; ++e4) {
      int eb = e4 * 4;
      float r0 = rc_lds[(eb + 0) * 32 + col];
      float r1 = rc_lds[(eb + 1) * 32 + col];
      float r2 = rc_lds[(eb + 2) * 32 + col];
      float r3 = rc_lds[(eb + 3) * 32 + col];
#pragma unroll
      for (int k = 0; k < 8; ++k) {
        float4 a = U2[(obase + k) * 32 + e4];
        accg[k] = fmaf(a.w, r3, fmaf(a.z, r2, fmaf(a.y, r1, fmaf(a.x, r0, accg[k]))));
      }
    }
#pragma unroll
    for (int k = 0; k < 8; ++k) {
      float uu = sigmoidf_(accu[k]);
      float gg = tanhf_(accg[k]);
      int idx = (obase + k) * 32 + col;
      c_lds[idx] = fmaf(uu, c_lds[idx] - gg, gg);  // u*c + (1-u)*g
    }
    __syncthreads();   // new c visible; everyone's rc reads done
  }

  // backward cell at t=H-1 with c0=0: h_back = (1-sigmoid(pre_u))*tanh(pre_g)
  {
    const float* mp = msg + ((size_t)(63 * 16 + b)) * 9 * 512 + n0 + col;
    const float* mb = msgb3 + (size_t)b * 3 * 512 + n0 + col;
    float mv[9];
#pragma unroll
    for (int j = 0; j < 6; ++j) mv[j] = mp[j * 512];
#pragma unroll
    for (int j = 0; j < 3; ++j) mv[6 + j] = mb[j * 512];
#pragma unroll
    for (int k = 0; k < 8; ++k) {
      int o = obase + k;
      float au = bb[128 + o], ag = bb[256 + o];
#pragma unroll
      for (int j = 0; j < 9; ++j) {
        au = fmaf(Wb[1152 + o * 9 + j], mv[j], au);
        ag = fmaf(Wb[2304 + o * 9 + j], mv[j], ag);
      }
      float uu = sigmoidf_(au);
      float gg = tanhf_(ag);
      rc_lds[o * 32 + col] = (1.f - uu) * gg;   // h_back
    }
  }
  __syncthreads();

  // decoder: hdec[i] = dec_b[i] + sum_e (dw[i,0,e]+dw[i,1,e]) * lt[e]
  if (tid < 12 * 32) {
    int i = tid >> 5, cc = tid & 31;
    const float* dwa = dec_w + (size_t)(i * 2) * 256;
    const float* dwb = dec_w + (size_t)(i * 2 + 1) * 256;
    float hd = dec_b[i];
    for (int e = 0; e < 128; ++e) {
      hd = fmaf(dwa[e] + dwb[e], c_lds[e * 32 + cc], hd);
      hd = fmaf(dwa[128 + e] + dwb[128 + e], rc_lds[e * 32 + cc], hd);
    }
    hdec[i * 32 + cc] = hd;
  }
  __syncthreads();
  if (tid < 12 * 32) {
    int o = tid >> 5, cc = tid & 31;
    float v = out_b[o];
#pragma unroll
    for (int i = 0; i < 12; ++i) v = fmaf(out_w[o * 12 + i], hdec[i * 32 + cc], v);
    out[((size_t)(b * 12 + o)) * 512 + n0 + cc] = v;
  }
}

extern "C" void kernel_launch(void* const* d_in, const int* in_sizes, int n_in,
                              void* d_out, int out_size, void* d_ws, size_t ws_size,
                              hipStream_t stream) {
  (void)in_sizes; (void)n_in; (void)out_size; (void)ws_size;
  const float* x     = (const float*)d_in[0];
  const float* adj   = (const float*)d_in[1];
  const float* Wf    = (const float*)d_in[2];
  const float* Uf    = (const float*)d_in[3];
  const float* bf    = (const float*)d_in[4];
  const float* E1f   = (const float*)d_in[5];
  const float* E2f   = (const float*)d_in[6];
  const float* Wb    = (const float*)d_in[7];
  const float* bb    = (const float*)d_in[9];
  const float* E1b   = (const float*)d_in[10];
  const float* E2b   = (const float*)d_in[11];
  const float* dec_w = (const float*)d_in[12];
  const float* dec_b = (const float*)d_in[13];
  const float* out_w = (const float*)d_in[14];
  const float* out_b = (const float*)d_in[15];

  float* ws    = (float*)d_ws;
  float* Af    = ws;                        // 512*512
  float* Ab    = ws + 512 * 512;            // 512*512
  float* msg   = ws + 2 * 512 * 512;        // 64*16*9*512
  float* msgb3 = msg + 64 * 16 * 9 * 512;   // 16*3*512

  dynadj_kernel<<<1024, 256, 0, stream>>>(E1f, E2f, E1b, E2b, Af, Ab);
  msg_kernel<<<1040, 256, 0, stream>>>(x, adj, Af, Ab, msg, msgb3);
  rec_kernel<<<256, 512, 0, stream>>>(msg, msgb3, Wf, Uf, bf, Wb, bb,
                                      dec_w, dec_b, out_w, out_b, (float*)d_out);
}

// Round 2
// 377.999 us; speedup vs baseline: 8.4877x; 8.4877x over previous
//
#include <hip/hip_runtime.h>

// IBNModel: graph-coupled bidirectional GRU + decoder.
// B=16, H=64, N=512, C=3, E=128, D=32, L_OUT=12, LAYERS=2. All fp32 in/out.
//
//  K1 dynadj_kernel : A_f, A_b = softmax(relu(E1 @ E2^T)) row-wise.       (ws)
//  K2 msg_kernel    : msg[t,b,0:9,n] = [xt, xt@adj, xt@A_f] for all t;    (ws)
//                     msgb3[b,0:3,n] = xt(H-1)@A_b (backward-only part).
//  K3 rec_kernel v2 : MFMA recurrence. Per step, per block (32 columns):
//                       gates = [U|W|b] @ [c; msg; 1]   (K=144 -> 5 kb of 32)
//                     via mfma_f32_16x16x32_f16. U/W/b fragments persist in
//                     registers; c state fp32 in registers (acc layout); only
//                     fp16 B-operand copies round-trip through LDS.

typedef _Float16 half8_t __attribute__((ext_vector_type(8)));
typedef float float4_t __attribute__((ext_vector_type(4)));

__device__ __forceinline__ float sigmoidf_(float x) { return 1.f / (1.f + __expf(-x)); }
__device__ __forceinline__ float tanhf_(float x) { return 1.f - 2.f / (__expf(2.f * x) + 1.f); }

// ---------------- K1: dynamic adjacency (softmax(relu(E1 E2^T))) ----------
__global__ __launch_bounds__(256) void dynadj_kernel(
    const float* __restrict__ E1f, const float* __restrict__ E2f,
    const float* __restrict__ E1b, const float* __restrict__ E2b,
    float* __restrict__ Af, float* __restrict__ Ab) {
  int bid = blockIdx.x;           // 0..1023 : [which][row]
  int which = bid >> 9;
  int row = bid & 511;
  const float* E1 = which ? E1b : E1f;
  const float* E2 = which ? E2b : E2f;
  float* A = which ? Ab : Af;
  __shared__ float e1[32];
  __shared__ float red[256];
  int tid = threadIdx.x;
  if (tid < 32) e1[tid] = E1[row * 32 + tid];
  __syncthreads();
  float s[2];
#pragma unroll
  for (int h = 0; h < 2; ++h) {
    int m = tid + h * 256;
    const float4* e2 = (const float4*)(E2 + m * 32);
    float acc = 0.f;
#pragma unroll
    for (int d4 = 0; d4 < 8; ++d4) {
      float4 v = e2[d4];
      acc = fmaf(v.x, e1[d4 * 4 + 0], acc);
      acc = fmaf(v.y, e1[d4 * 4 + 1], acc);
      acc = fmaf(v.z, e1[d4 * 4 + 2], acc);
      acc = fmaf(v.w, e1[d4 * 4 + 3], acc);
    }
    s[h] = fmaxf(acc, 0.f);      // relu
  }
  red[tid] = fmaxf(s[0], s[1]);
  __syncthreads();
  for (int off = 128; off > 0; off >>= 1) {
    if (tid < off) red[tid] = fmaxf(red[tid], red[tid + off]);
    __syncthreads();
  }
  float mx = red[0];
  __syncthreads();
  float e0 = __expf(s[0] - mx), e1v = __expf(s[1] - mx);
  red[tid] = e0 + e1v;
  __syncthreads();
  for (int off = 128; off > 0; off >>= 1) {
    if (tid < off) red[tid] += red[tid + off];
    __syncthreads();
  }
  float inv = 1.f / red[0];
  A[row * 512 + tid] = e0 * inv;
  A[row * 512 + tid + 256] = e1v * inv;
}

// ---------------- K2: message precompute --------------------------------
// msg layout: msg[((t*16+b)*9 + ch)*512 + n]
__global__ __launch_bounds__(256) void msg_kernel(
    const float* __restrict__ x, const float* __restrict__ adj,
    const float* __restrict__ Af, const float* __restrict__ Ab,
    float* __restrict__ msg, float* __restrict__ msgb3) {
  int bid = blockIdx.x;
  __shared__ float xls[3 * 512];
  int tid = threadIdx.x;
  int t, b;
  bool back;
  if (bid < 1024) { t = bid >> 4; b = bid & 15; back = false; }
  else            { t = 63; b = bid - 1024; back = true; }
  const float* xp = x + ((size_t)(b * 64 + t)) * 512 * 3;
#pragma unroll
  for (int i = 0; i < 6; ++i) {
    int j = tid + i * 256;
    float v = xp[j];
    int n = j / 3, c = j - n * 3;
    xls[c * 512 + n] = v;       // transpose to [c][n]
  }
  __syncthreads();
  const float* Ad = back ? Ab : Af;
  float accp[3][2] = {{0.f, 0.f}, {0.f, 0.f}, {0.f, 0.f}};
  float accd[3][2] = {{0.f, 0.f}, {0.f, 0.f}, {0.f, 0.f}};
  for (int n = 0; n < 512; ++n) {
    float x0 = xls[n], x1 = xls[512 + n], x2 = xls[1024 + n];
    float a0 = adj[n * 512 + tid], a1 = adj[n * 512 + tid + 256];
    float d0 = Ad[n * 512 + tid], d1 = Ad[n * 512 + tid + 256];
    accp[0][0] = fmaf(x0, a0, accp[0][0]);
    accp[1][0] = fmaf(x1, a0, accp[1][0]);
    accp[2][0] = fmaf(x2, a0, accp[2][0]);
    accp[0][1] = fmaf(x0, a1, accp[0][1]);
    accp[1][1] = fmaf(x1, a1, accp[1][1]);
    accp[2][1] = fmaf(x2, a1, accp[2][1]);
    accd[0][0] = fmaf(x0, d0, accd[0][0]);
    accd[1][0] = fmaf(x1, d0, accd[1][0]);
    accd[2][0] = fmaf(x2, d0, accd[2][0]);
    accd[0][1] = fmaf(x0, d1, accd[0][1]);
    accd[1][1] = fmaf(x1, d1, accd[1][1]);
    accd[2][1] = fmaf(x2, d1, accd[2][1]);
  }
  if (!back) {
    float* mp = msg + ((size_t)(t * 16 + b)) * 9 * 512;
#pragma unroll
    for (int h = 0; h < 2; ++h) {
      int m = tid + h * 256;
      mp[0 * 512 + m] = xls[m];
      mp[1 * 512 + m] = xls[512 + m];
      mp[2 * 512 + m] = xls[1024 + m];
      mp[3 * 512 + m] = accp[0][h];
      mp[4 * 512 + m] = accp[1][h];
      mp[5 * 512 + m] = accp[2][h];
      mp[6 * 512 + m] = accd[0][h];
      mp[7 * 512 + m] = accd[1][h];
      mp[8 * 512 + m] = accd[2][h];
    }
  } else {
    float* mp = msgb3 + (size_t)b * 3 * 512;
#pragma unroll
    for (int h = 0; h < 2; ++h) {
      int m = tid + h * 256;
      mp[0 * 512 + m] = accd[0][h];
      mp[1 * 512 + m] = accd[1][h];
      mp[2 * 512 + m] = accd[2][h];
    }
  }
}

// ---------------- K3: MFMA recurrence + backward + decoder ---------------
// 256 blocks (b 0..15 x ntile 0..15, 32 cols each), 256 threads = 4 waves.
// Wave og owns output rows [og*32, og*32+32) as 2 row-tiles of 16.
// Columns: 2 col-tiles of 16. K augmented to 160: kb0..3 = U (128),
// kb4 = [W(9) | bias(1) | 0...] with B rows [msg(9); 1; 0...].
//
// Bbuf fp16, wave-linear frag layout: region (kb*2+ct), 64 lanes x 8 halves:
//   Bbuf[((kb*2+ct)*64 + lane)*8 + j] = Bmat[k = kb*32 + (lane>>4)*8 + j][n = ct*16 + (lane&15)]
// Bgbuf same for the r*c operand (kb0..3 only).
__global__ __launch_bounds__(256, 1) void rec_kernel(
    const float* __restrict__ msg, const float* __restrict__ msgb3,
    const float* __restrict__ Wf, const float* __restrict__ Uf,
    const float* __restrict__ bf, const float* __restrict__ Wb,
    const float* __restrict__ bb, const float* __restrict__ dec_w,
    const float* __restrict__ dec_b, const float* __restrict__ out_w,
    const float* __restrict__ out_b, float* __restrict__ out) {
  __shared__ __align__(16) _Float16 Bbuf[10 * 64 * 8];   // 10240 B
  __shared__ __align__(16) _Float16 Bgbuf[8 * 64 * 8];   // 8192 B
  __shared__ float hf_lds[128 * 32];
  __shared__ float hb_lds[128 * 32];
  __shared__ float hdec_lds[12 * 32];

  int tid = threadIdx.x;
  int bid = blockIdx.x;
  int b = bid >> 4;
  int n0 = (bid & 15) * 32;
  int lane = tid & 63;
  int og = tid >> 6;
  int l15 = lane & 15;
  int q4 = lane >> 4;          // 0..3
  int q0 = q4 * 8;             // k base within a kb for this lane

  // ---- load persistent A fragments: [gate][row-tile][kb] -----------------
  half8_t afrag[3][2][5];
#pragma unroll
  for (int gi = 0; gi < 3; ++gi) {
#pragma unroll
    for (int rt = 0; rt < 2; ++rt) {
      int o = og * 32 + rt * 16 + l15;
#pragma unroll
      for (int kb = 0; kb < 4; ++kb) {
        const float* p = Uf + gi * 16384 + o * 128 + kb * 32 + q0;
        half8_t f;
#pragma unroll
        for (int j = 0; j < 8; ++j) f[j] = (_Float16)p[j];
        afrag[gi][rt][kb] = f;
      }
      half8_t f;
#pragma unroll
      for (int j = 0; j < 8; ++j) {
        int q = q0 + j;
        float v = (q < 9) ? Wf[gi * 1152 + o * 9 + q]
                          : (q == 9 ? bf[gi * 128 + o] : 0.f);
        f[j] = (_Float16)v;
      }
      afrag[gi][rt][4] = f;
    }
  }

  // ---- init: c = 0 (regs + LDS fp16 copy), msg block for t=0 -------------
  float cr[2][2][4];   // [rt][ct][reg] : row = og*32+rt*16+q4*4+reg, col = ct*16+l15
#pragma unroll
  for (int rt = 0; rt < 2; ++rt)
#pragma unroll
    for (int ct = 0; ct < 2; ++ct)
#pragma unroll
      for (int r = 0; r < 4; ++r) cr[rt][ct][r] = 0.f;
  for (int i = tid; i < 8 * 64 * 8; i += 256) Bbuf[i] = (_Float16)0.f;  // c regions
  if (og < 2) {
    const float* mp = msg + ((size_t)(0 * 16 + b)) * 9 * 512 + n0 + og * 16 + l15;
    half8_t f;
#pragma unroll
    for (int j = 0; j < 8; ++j) {
      int q = q0 + j;
      float v = 0.f;
      if (q < 9) v = mp[q * 512];
      else if (q == 9) v = 1.f;
      f[j] = (_Float16)v;
    }
    *(half8_t*)&Bbuf[((8 + og) * 64 + lane) * 8] = f;
  }
  __syncthreads();

  union H4U { _Float16 h[4]; unsigned long long u; };
  const float4_t zero4 = {0.f, 0.f, 0.f, 0.f};

  // ---- recurrence ---------------------------------------------------------
  for (int t = 0; t < 64; ++t) {
    // prefetch msg_{t+1} into regs (waves 0,1)
    float pf[8];
    if (og < 2 && t < 63) {
      const float* mp = msg + ((size_t)((t + 1) * 16 + b)) * 9 * 512 + n0 + og * 16 + l15;
#pragma unroll
      for (int j = 0; j < 8; ++j) {
        int q = q0 + j;
        pf[j] = (q < 9) ? mp[q * 512] : (q == 9 ? 1.f : 0.f);
      }
    }

    // load B frags (c + msg), phase 1: r,u gates
    half8_t bfr[2][5];
#pragma unroll
    for (int ct = 0; ct < 2; ++ct)
#pragma unroll
      for (int kb = 0; kb < 5; ++kb)
        bfr[ct][kb] = *(const half8_t*)&Bbuf[((kb * 2 + ct) * 64 + lane) * 8];

    float4_t accr[2][2], accu[2][2];
#pragma unroll
    for (int rt = 0; rt < 2; ++rt)
#pragma unroll
      for (int ct = 0; ct < 2; ++ct) { accr[rt][ct] = zero4; accu[rt][ct] = zero4; }
#pragma unroll
    for (int kb = 0; kb < 5; ++kb)
#pragma unroll
      for (int rt = 0; rt < 2; ++rt)
#pragma unroll
        for (int ct = 0; ct < 2; ++ct) {
          accr[rt][ct] = __builtin_amdgcn_mfma_f32_16x16x32_f16(
              afrag[0][rt][kb], bfr[ct][kb], accr[rt][ct], 0, 0, 0);
          accu[rt][ct] = __builtin_amdgcn_mfma_f32_16x16x32_f16(
              afrag[1][rt][kb], bfr[ct][kb], accu[rt][ct], 0, 0, 0);
        }

    // r = sigmoid(.), rc = r*c -> Bgbuf (wave og writes kb=og region)
#pragma unroll
    for (int rt = 0; rt < 2; ++rt)
#pragma unroll
      for (int ct = 0; ct < 2; ++ct) {
        H4U v;
#pragma unroll
        for (int r = 0; r < 4; ++r) {
          float rr = sigmoidf_(accr[rt][ct][r]);
          v.h[r] = (_Float16)(rr * cr[rt][ct][r]);
        }
        int lane_t = (rt * 2 + (q4 >> 1)) * 16 + l15;
        *(unsigned long long*)&Bgbuf[((og * 2 + ct) * 64 + lane_t) * 8 + (q4 & 1) * 4] = v.u;
      }
    __syncthreads();  // B1: rc visible; all Bbuf reads done

    // phase 2: g gate (U2 @ rc over kb0..3, +[W|b] @ [msg;1] via bfr[ct][4])
    half8_t bgf[2][4];
#pragma unroll
    for (int ct = 0; ct < 2; ++ct)
#pragma unroll
      for (int kb = 0; kb < 4; ++kb)
        bgf[ct][kb] = *(const half8_t*)&Bgbuf[((kb * 2 + ct) * 64 + lane) * 8];

    float4_t accg[2][2];
#pragma unroll
    for (int rt = 0; rt < 2; ++rt)
#pragma unroll
      for (int ct = 0; ct < 2; ++ct) {
        float4_t a = zero4;
#pragma unroll
        for (int kb = 0; kb < 4; ++kb)
          a = __builtin_amdgcn_mfma_f32_16x16x32_f16(afrag[2][rt][kb], bgf[ct][kb], a, 0, 0, 0);
        a = __builtin_amdgcn_mfma_f32_16x16x32_f16(afrag[2][rt][4], bfr[ct][4], a, 0, 0, 0);
        accg[rt][ct] = a;
      }

    // update c (fp32 regs) and write fp16 copy to Bbuf (kb=og region)
#pragma unroll
    for (int rt = 0; rt < 2; ++rt)
#pragma unroll
      for (int ct = 0; ct < 2; ++ct) {
        H4U v;
#pragma unroll
        for (int r = 0; r < 4; ++r) {
          float uu = sigmoidf_(accu[rt][ct][r]);
          float gg = tanhf_(accg[rt][ct][r]);
          float cn = fmaf(uu, cr[rt][ct][r] - gg, gg);  // u*c + (1-u)*g
          cr[rt][ct][r] = cn;
          v.h[r] = (_Float16)cn;
        }
        int lane_t = (rt * 2 + (q4 >> 1)) * 16 + l15;
        *(unsigned long long*)&Bbuf[((og * 2 + ct) * 64 + lane_t) * 8 + (q4 & 1) * 4] = v.u;
      }
    // write msg_{t+1}
    if (og < 2 && t < 63) {
      half8_t f;
#pragma unroll
      for (int j = 0; j < 8; ++j) f[j] = (_Float16)pf[j];
      *(half8_t*)&Bbuf[((8 + og) * 64 + lane) * 8] = f;
    }
    __syncthreads();  // B2: c_{t+1}, msg_{t+1} visible; Bg reads done
  }

  // ---- backward cell at t=63, c0=0: h_back = (1-sig(pre_u))*tanh(pre_g) ---
  // B block (K=32): k<6 -> msg63 ch k; 6..8 -> msgb3; 9 -> 1; else 0.
  if (og < 2) {
    const float* mp63 = msg + ((size_t)(63 * 16 + b)) * 9 * 512 + n0 + og * 16 + l15;
    const float* mb = msgb3 + (size_t)b * 3 * 512 + n0 + og * 16 + l15;
    half8_t f;
#pragma unroll
    for (int j = 0; j < 8; ++j) {
      int q = q0 + j;
      float v = 0.f;
      if (q < 6) v = mp63[q * 512];
      else if (q < 9) v = mb[(q - 6) * 512];
      else if (q == 9) v = 1.f;
      f[j] = (_Float16)v;
    }
    *(half8_t*)&Bgbuf[(og * 64 + lane) * 8] = f;
  }
  // backward A frags: gates u(1), g(2)
  half8_t abk[2][2];  // [gi-1][rt]
#pragma unroll
  for (int gi = 1; gi < 3; ++gi)
#pragma unroll
    for (int rt = 0; rt < 2; ++rt) {
      int o = og * 32 + rt * 16 + l15;
      half8_t f;
#pragma unroll
      for (int j = 0; j < 8; ++j) {
        int q = q0 + j;
        float v = (q < 9) ? Wb[gi * 1152 + o * 9 + q]
                          : (q == 9 ? bb[gi * 128 + o] : 0.f);
        f[j] = (_Float16)v;
      }
      abk[gi - 1][rt] = f;
    }
  __syncthreads();

  {
    half8_t bbk[2];
#pragma unroll
    for (int ct = 0; ct < 2; ++ct)
      bbk[ct] = *(const half8_t*)&Bgbuf[(ct * 64 + lane) * 8];
#pragma unroll
    for (int rt = 0; rt < 2; ++rt)
#pragma unroll
      for (int ct = 0; ct < 2; ++ct) {
        float4_t au = __builtin_amdgcn_mfma_f32_16x16x32_f16(abk[0][rt], bbk[ct], zero4, 0, 0, 0);
        float4_t ag = __builtin_amdgcn_mfma_f32_16x16x32_f16(abk[1][rt], bbk[ct], zero4, 0, 0, 0);
        int col = ct * 16 + l15;
#pragma unroll
        for (int r = 0; r < 4; ++r) {
          int row = og * 32 + rt * 16 + q4 * 4 + r;
          float uu = sigmoidf_(au[r]);
          float gg = tanhf_(ag[r]);
          hb_lds[row * 32 + col] = (1.f - uu) * gg;
          hf_lds[row * 32 + col] = cr[rt][ct][r];
        }
      }
  }
  __syncthreads();

  // ---- decoder: hdec[i] = dec_b[i] + sum_e dw2[i,e]*hf[e] + dw2[i,128+e]*hb[e]
  {
    int cc = tid & 31;
    for (int i = tid >> 5; i < 12; i += 8) {
      const float* dwa = dec_w + (size_t)i * 512;        // layer 0
      const float* dwb = dec_w + (size_t)i * 512 + 256;  // layer 1
      float hd = dec_b[i];
      for (int e = 0; e < 128; ++e) {
        hd = fmaf(dwa[e] + dwb[e], hf_lds[e * 32 + cc], hd);
        hd = fmaf(dwa[128 + e] + dwb[128 + e], hb_lds[e * 32 + cc], hd);
      }
      hdec_lds[i * 32 + cc] = hd;
    }
  }
  __syncthreads();
  {
    int cc = tid & 31;
    for (int o = tid >> 5; o < 12; o += 8) {
      float v = out_b[o];
#pragma unroll
      for (int i = 0; i < 12; ++i) v = fmaf(out_w[o * 12 + i], hdec_lds[i * 32 + cc], v);
      out[((size_t)(b * 12 + o)) * 512 + n0 + cc] = v;
    }
  }
}

extern "C" void kernel_launch(void* const* d_in, const int* in_sizes, int n_in,
                              void* d_out, int out_size, void* d_ws, size_t ws_size,
                              hipStream_t stream) {
  (void)in_sizes; (void)n_in; (void)out_size; (void)ws_size;
  const float* x     = (const float*)d_in[0];
  const float* adj   = (const float*)d_in[1];
  const float* Wf    = (const float*)d_in[2];
  const float* Uf    = (const float*)d_in[3];
  const float* bf    = (const float*)d_in[4];
  const float* E1f   = (const float*)d_in[5];
  const float* E2f   = (const float*)d_in[6];
  const float* Wb    = (const float*)d_in[7];
  const float* bb    = (const float*)d_in[9];
  const float* E1b   = (const float*)d_in[10];
  const float* E2b   = (const float*)d_in[11];
  const float* dec_w = (const float*)d_in[12];
  const float* dec_b = (const float*)d_in[13];
  const float* out_w = (const float*)d_in[14];
  const float* out_b = (const float*)d_in[15];

  float* ws    = (float*)d_ws;
  float* Af    = ws;                        // 512*512
  float* Ab    = ws + 512 * 512;            // 512*512
  float* msg   = ws + 2 * 512 * 512;        // 64*16*9*512
  float* msgb3 = msg + 64 * 16 * 9 * 512;   // 16*3*512

  dynadj_kernel<<<1024, 256, 0, stream>>>(E1f, E2f, E1b, E2b, Af, Ab);
  msg_kernel<<<1040, 256, 0, stream>>>(x, adj, Af, Ab, msg, msgb3);
  rec_kernel<<<256, 256, 0, stream>>>(msg, msgb3, Wf, Uf, bf, Wb, bb,
                                      dec_w, dec_b, out_w, out_b, (float*)d_out);
}

// Round 3
// 306.529 us; speedup vs baseline: 10.4667x; 1.2332x over previous
//
#include <hip/hip_runtime.h>

// IBNModel: graph-coupled bidirectional GRU + decoder. All fp32 in/out.
// B=16, H=64, N=512, C=3, E=128, D=32, L_OUT=12, LAYERS=2.
//
//  K1 prep_kernel : A_f,A_b = softmax(relu(E1 E2^T)) -> fp16 TRANSPOSED copies
//                   AfT/AbT [col][row]; also adj -> adjT fp16 [col][row].
//  K2 msg_kernel  : MFMA GEMM. M=(t,b,c)=3072, K=512(n), B = adjT/AfT (+AbT
//                   for t=63). Writes msg16 fp16 in rec's layout:
//                   msg16[(t*16+b)][n][k16]  k0-2=x, k3-5=x@adj, k6-8=x@Af,
//                   k9=1.0 (k10-15 unwritten: multiplied by zero A rows).
//                   msgb16[b][n][k16] same with k6-8 = x@Ab (t=63).
//  K3 rec_kernel  : MFMA recurrence, 16 cols/block, 512 blocks (2/CU).
//                   Whole 64-step msg slice preloaded to LDS (no global in
//                   loop). U/W/b frags persist in regs; c fp32 in regs.

typedef _Float16 half8_t __attribute__((ext_vector_type(8)));
typedef float float4_t __attribute__((ext_vector_type(4)));

__device__ __forceinline__ float sigmoidf_(float x) { return 1.f / (1.f + __expf(-x)); }
__device__ __forceinline__ float tanhf_(float x) { return 1.f - 2.f / (__expf(2.f * x) + 1.f); }

// ---------------- K1: dynamic adjacency + fp16 transposes -----------------
__global__ __launch_bounds__(256) void prep_kernel(
    const float* __restrict__ E1f, const float* __restrict__ E2f,
    const float* __restrict__ E1b, const float* __restrict__ E2b,
    const float* __restrict__ adj, _Float16* __restrict__ adjT,
    _Float16* __restrict__ AfT, _Float16* __restrict__ AbT) {
  int bid = blockIdx.x;
  int tid = threadIdx.x;
  if (bid >= 1024) {  // adj -> adjT fp16 (transpose)
    int base = (bid - 1024) * 4;
    for (int r = 0; r < 4; ++r) {
      int row = base + r;
      float v0 = adj[row * 512 + tid];
      float v1 = adj[row * 512 + tid + 256];
      adjT[(size_t)tid * 512 + row] = (_Float16)v0;
      adjT[(size_t)(tid + 256) * 512 + row] = (_Float16)v1;
    }
    return;
  }
  int which = bid >> 9;
  int row = bid & 511;
  const float* E1 = which ? E1b : E1f;
  const float* E2 = which ? E2b : E2f;
  _Float16* A = which ? AbT : AfT;
  __shared__ float e1s[32];
  __shared__ float red[256];
  if (tid < 32) e1s[tid] = E1[row * 32 + tid];
  __syncthreads();
  float s[2];
#pragma unroll
  for (int h = 0; h < 2; ++h) {
    int m = tid + h * 256;
    const float4* e2 = (const float4*)(E2 + m * 32);
    float acc = 0.f;
#pragma unroll
    for (int d4 = 0; d4 < 8; ++d4) {
      float4 v = e2[d4];
      acc = fmaf(v.x, e1s[d4 * 4 + 0], acc);
      acc = fmaf(v.y, e1s[d4 * 4 + 1], acc);
      acc = fmaf(v.z, e1s[d4 * 4 + 2], acc);
      acc = fmaf(v.w, e1s[d4 * 4 + 3], acc);
    }
    s[h] = fmaxf(acc, 0.f);
  }
  red[tid] = fmaxf(s[0], s[1]);
  __syncthreads();
  for (int off = 128; off > 0; off >>= 1) {
    if (tid < off) red[tid] = fmaxf(red[tid], red[tid + off]);
    __syncthreads();
  }
  float mx = red[0];
  __syncthreads();
  float e0 = __expf(s[0] - mx), e1v = __expf(s[1] - mx);
  red[tid] = e0 + e1v;
  __syncthreads();
  for (int off = 128; off > 0; off >>= 1) {
    if (tid < off) red[tid] += red[tid + off];
    __syncthreads();
  }
  float inv = 1.f / red[0];
  A[(size_t)tid * 512 + row] = (_Float16)(e0 * inv);          // transposed
  A[(size_t)(tid + 256) * 512 + row] = (_Float16)(e1v * inv);
}

// ---------------- K2: message GEMM (MFMA) --------------------------------
// grid 256 = t(64) x nc(4); 256 threads = 4 waves. Block: Mtile=48 (fixed t,
// m = b*3+c), Ntile=128 (n0g..+127). Wave og owns n16 tiles {og*2, og*2+1}.
// A staged in LDS [48][512] fp16, XOR-swizzled in 8-half units to kill the
// stride-512 16-way bank conflict on A-frag reads.
__global__ __launch_bounds__(256) void msg_kernel(
    const float* __restrict__ x, const _Float16* __restrict__ adjT,
    const _Float16* __restrict__ AfT, const _Float16* __restrict__ AbT,
    _Float16* __restrict__ msg16, _Float16* __restrict__ msgb16) {
  __shared__ __align__(16) _Float16 Alds[48 * 512];  // 48 KB
  int tid = threadIdx.x;
  int t = blockIdx.x >> 2;
  int n0g = (blockIdx.x & 3) * 128;
  int lane = tid & 63, og = tid >> 6;
  int l15 = lane & 15, q4 = lane >> 4, q0 = q4 * 8;
  bool is63 = (t == 63);

  // stage A: x[b][t][n][c] -> Alds[m=b*3+c][k=n] (swizzled)
  {
    int b = tid >> 4, nch = tid & 15;
    const float4* x4 = (const float4*)(x + ((size_t)(b * 64 + t)) * 1536 + nch * 96);
#pragma unroll
    for (int i = 0; i < 24; ++i) {
      float4 v = x4[i];
#pragma unroll
      for (int l = 0; l < 4; ++l) {
        int jj = i * 4 + l;
        int nn = jj / 3, cc = jj - nn * 3;          // compile-time per (i,l)
        int n = nch * 32 + nn;
        int m = b * 3 + cc;
        float val = (l == 0) ? v.x : (l == 1) ? v.y : (l == 2) ? v.z : v.w;
        Alds[m * 512 + ((((n >> 3) ^ (m & 7)) << 3) | (n & 7))] = (_Float16)val;
      }
    }
  }
  __syncthreads();

  const float4_t zero4 = {0.f, 0.f, 0.f, 0.f};
  float4_t acc[3][2][2];   // [mt][ntl][mat 0=adj,1=Af]
  float4_t accb[3][2];     // t63: Ab
#pragma unroll
  for (int mt = 0; mt < 3; ++mt)
#pragma unroll
    for (int ntl = 0; ntl < 2; ++ntl) {
      acc[mt][ntl][0] = zero4; acc[mt][ntl][1] = zero4; accb[mt][ntl] = zero4;
    }

  for (int kb = 0; kb < 16; ++kb) {
    half8_t afr[3];
#pragma unroll
    for (int mt = 0; mt < 3; ++mt) {
      int m = mt * 16 + l15;
      afr[mt] = *(const half8_t*)&Alds[m * 512 + ((((kb * 4 + q4) ^ (m & 7)) << 3))];
    }
#pragma unroll
    for (int ntl = 0; ntl < 2; ++ntl) {
      int n = n0g + (og * 2 + ntl) * 16 + l15;
      half8_t b0 = *(const half8_t*)&adjT[(size_t)n * 512 + kb * 32 + q0];
      half8_t b1 = *(const half8_t*)&AfT[(size_t)n * 512 + kb * 32 + q0];
#pragma unroll
      for (int mt = 0; mt < 3; ++mt) {
        acc[mt][ntl][0] = __builtin_amdgcn_mfma_f32_16x16x32_f16(afr[mt], b0, acc[mt][ntl][0], 0, 0, 0);
        acc[mt][ntl][1] = __builtin_amdgcn_mfma_f32_16x16x32_f16(afr[mt], b1, acc[mt][ntl][1], 0, 0, 0);
      }
      if (is63) {
        half8_t b2 = *(const half8_t*)&AbT[(size_t)n * 512 + kb * 32 + q0];
#pragma unroll
        for (int mt = 0; mt < 3; ++mt)
          accb[mt][ntl] = __builtin_amdgcn_mfma_f32_16x16x32_f16(afr[mt], b2, accb[mt][ntl], 0, 0, 0);
      }
    }
  }

  // epilogue: x-copy (k0-2) + ones (k9), direct fp16 global stores
  for (int i = tid; i < 2048; i += 256) {
    int tb = i >> 7, nloc = i & 127;
    int n = n0g + nloc;
    _Float16* o = msg16 + ((size_t)(t * 16 + tb) * 512 + n) * 16;
#pragma unroll
    for (int c = 0; c < 3; ++c) {
      int m = tb * 3 + c;
      o[c] = Alds[m * 512 + ((((n >> 3) ^ (m & 7)) << 3) | (n & 7))];
    }
    o[9] = (_Float16)1.f;
  }
  // MFMA results: C layout col=lane&15, row=q4*4+r
#pragma unroll
  for (int mt = 0; mt < 3; ++mt)
#pragma unroll
    for (int ntl = 0; ntl < 2; ++ntl) {
      int n = n0g + (og * 2 + ntl) * 16 + l15;
#pragma unroll
      for (int r = 0; r < 4; ++r) {
        int m = mt * 16 + q4 * 4 + r;
        int tb = m / 3, c = m - tb * 3;
        _Float16* o = msg16 + ((size_t)(t * 16 + tb) * 512 + n) * 16;
        o[3 + c] = (_Float16)acc[mt][ntl][0][r];
        o[6 + c] = (_Float16)acc[mt][ntl][1][r];
      }
    }
  if (is63) {
    for (int i = tid; i < 2048; i += 256) {
      int tb = i >> 7, nloc = i & 127;
      int n = n0g + nloc;
      _Float16* o = msgb16 + ((size_t)tb * 512 + n) * 16;
#pragma unroll
      for (int c = 0; c < 3; ++c) {
        int m = tb * 3 + c;
        o[c] = Alds[m * 512 + ((((n >> 3) ^ (m & 7)) << 3) | (n & 7))];
      }
      o[9] = (_Float16)1.f;
    }
#pragma unroll
    for (int mt = 0; mt < 3; ++mt)
#pragma unroll
      for (int ntl = 0; ntl < 2; ++ntl) {
        int n = n0g + (og * 2 + ntl) * 16 + l15;
#pragma unroll
        for (int r = 0; r < 4; ++r) {
          int m = mt * 16 + q4 * 4 + r;
          int tb = m / 3, c = m - tb * 3;
          _Float16* o = msgb16 + ((size_t)tb * 512 + n) * 16;
          o[3 + c] = (_Float16)acc[mt][ntl][0][r];   // adj product (shared)
          o[6 + c] = (_Float16)accb[mt][ntl][r];     // Ab product
        }
      }
  }
}

// ---------------- K3: MFMA recurrence + backward + decoder ---------------
// grid 512 = b(16) x ntile(32), 16 cols each; 256 threads = 4 waves -> 2
// blocks/CU (LDS 58 KB, VGPR ~172). Wave og owns rows [og*32, og*32+32).
// K blocks: kb0-3 = U over c (K=128), kb4 = [W(9)|b(1)|0..] over [msg;1;0..].
// Frag layout in Cbuf/Gbuf: [kb][lane][8]: val[k=kb*32+(lane>>4)*8+j][n=lane&15].
__global__ __launch_bounds__(256, 2) void rec_kernel(
    const _Float16* __restrict__ msg16, const _Float16* __restrict__ msgb16,
    const float* __restrict__ Wf, const float* __restrict__ Uf,
    const float* __restrict__ bf, const float* __restrict__ Wb,
    const float* __restrict__ bb, const float* __restrict__ dec_w,
    const float* __restrict__ dec_b, const float* __restrict__ out_w,
    const float* __restrict__ out_b, float* __restrict__ out) {
  __shared__ __align__(16) _Float16 Bmsg[64 * 16 * 16];  // 32 KB: [t][n16][k16]
  __shared__ __align__(16) _Float16 Cbuf[4 * 64 * 8];    // 4 KB
  __shared__ __align__(16) _Float16 Gbuf[4 * 64 * 8];    // 4 KB
  __shared__ float hf_lds[128 * 16];
  __shared__ float hb_lds[128 * 16];
  __shared__ float hdec_lds[12 * 16];
  int tid = threadIdx.x, bid = blockIdx.x;
  int b = bid >> 5;
  int n0 = (bid & 31) * 16;
  int lane = tid & 63, og = tid >> 6;
  int l15 = lane & 15, q4 = lane >> 4, q0 = q4 * 8;

  // persistent A frags [gate][rt][kb]
  half8_t afrag[3][2][5];
#pragma unroll
  for (int gi = 0; gi < 3; ++gi)
#pragma unroll
    for (int rt = 0; rt < 2; ++rt) {
      int o = og * 32 + rt * 16 + l15;
#pragma unroll
      for (int kb = 0; kb < 4; ++kb) {
        const float* p = Uf + gi * 16384 + o * 128 + kb * 32 + q0;
        half8_t f;
#pragma unroll
        for (int j = 0; j < 8; ++j) f[j] = (_Float16)p[j];
        afrag[gi][rt][kb] = f;
      }
      half8_t f;
#pragma unroll
      for (int j = 0; j < 8; ++j) {
        int q = q0 + j;
        float v = (q < 9) ? Wf[gi * 1152 + o * 9 + q]
                          : (q == 9 ? bf[gi * 128 + o] : 0.f);
        f[j] = (_Float16)v;
      }
      afrag[gi][rt][4] = f;
    }

  // preload full 64-step msg slice (coalesced uint4 copy)
  {
    const uint4* src = (const uint4*)msg16;
    uint4* dst = (uint4*)Bmsg;
    for (int f = tid; f < 2048; f += 256) {
      int t = f >> 5, off = f & 31;
      dst[f] = src[((size_t)(t * 16 + b) * 512 + n0) * 2 + off];
    }
  }
  {
    uint4 z; z.x = z.y = z.z = z.w = 0;
    ((uint4*)Cbuf)[tid] = z;  // 256 uint4 = 4 KB
  }
  float cr[2][4];
#pragma unroll
  for (int rt = 0; rt < 2; ++rt)
#pragma unroll
    for (int r = 0; r < 4; ++r) cr[rt][r] = 0.f;
  __syncthreads();

  const float4_t zero4 = {0.f, 0.f, 0.f, 0.f};
  union H4U { _Float16 h[4]; unsigned long long u; };
  int lane_q = (q4 & 1) * 8;  // q4>=2 lanes alias k0-15 (x A-zeros => harmless)

  for (int t = 0; t < 64; ++t) {
    half8_t bmsg = *(const half8_t*)&Bmsg[t * 256 + l15 * 16 + lane_q];
    half8_t cf[4];
#pragma unroll
    for (int kb = 0; kb < 4; ++kb)
      cf[kb] = *(const half8_t*)&Cbuf[(kb * 64 + lane) * 8];

    float4_t accr[2], accu[2];
    accr[0] = accr[1] = accu[0] = accu[1] = zero4;
#pragma unroll
    for (int kb = 0; kb < 4; ++kb)
#pragma unroll
      for (int rt = 0; rt < 2; ++rt) {
        accr[rt] = __builtin_amdgcn_mfma_f32_16x16x32_f16(afrag[0][rt][kb], cf[kb], accr[rt], 0, 0, 0);
        accu[rt] = __builtin_amdgcn_mfma_f32_16x16x32_f16(afrag[1][rt][kb], cf[kb], accu[rt], 0, 0, 0);
      }
#pragma unroll
    for (int rt = 0; rt < 2; ++rt) {
      accr[rt] = __builtin_amdgcn_mfma_f32_16x16x32_f16(afrag[0][rt][4], bmsg, accr[rt], 0, 0, 0);
      accu[rt] = __builtin_amdgcn_mfma_f32_16x16x32_f16(afrag[1][rt][4], bmsg, accu[rt], 0, 0, 0);
    }
#pragma unroll
    for (int rt = 0; rt < 2; ++rt) {
      H4U v;
#pragma unroll
      for (int r = 0; r < 4; ++r)
        v.h[r] = (_Float16)(sigmoidf_(accr[rt][r]) * cr[rt][r]);
      int lane_t = (rt * 2 + (q4 >> 1)) * 16 + l15;
      *(unsigned long long*)&Gbuf[(og * 64 + lane_t) * 8 + (q4 & 1) * 4] = v.u;
    }
    __syncthreads();  // rc visible; Cbuf reads done

    half8_t gf[4];
#pragma unroll
    for (int kb = 0; kb < 4; ++kb)
      gf[kb] = *(const half8_t*)&Gbuf[(kb * 64 + lane) * 8];
    float4_t accg[2];
#pragma unroll
    for (int rt = 0; rt < 2; ++rt) {
      float4_t a = zero4;
#pragma unroll
      for (int kb = 0; kb < 4; ++kb)
        a = __builtin_amdgcn_mfma_f32_16x16x32_f16(afrag[2][rt][kb], gf[kb], a, 0, 0, 0);
      a = __builtin_amdgcn_mfma_f32_16x16x32_f16(afrag[2][rt][4], bmsg, a, 0, 0, 0);
      accg[rt] = a;
    }
#pragma unroll
    for (int rt = 0; rt < 2; ++rt) {
      H4U v;
#pragma unroll
      for (int r = 0; r < 4; ++r) {
        float uu = sigmoidf_(accu[rt][r]);
        float gg = tanhf_(accg[rt][r]);
        float cn = fmaf(uu, cr[rt][r] - gg, gg);  // u*c + (1-u)*g
        cr[rt][r] = cn;
        v.h[r] = (_Float16)cn;
      }
      int lane_t = (rt * 2 + (q4 >> 1)) * 16 + l15;
      *(unsigned long long*)&Cbuf[(og * 64 + lane_t) * 8 + (q4 & 1) * 4] = v.u;
    }
    __syncthreads();  // c_{t+1} visible; Gbuf reads done
  }

  // backward cell at t=63, c0=0: h_back = (1-sig(pre_u))*tanh(pre_g)
  {
    half8_t bbk = *(const half8_t*)&msgb16[((size_t)b * 512 + n0 + l15) * 16 + lane_q];
    half8_t abk[2][2];
#pragma unroll
    for (int gi = 1; gi < 3; ++gi)
#pragma unroll
      for (int rt = 0; rt < 2; ++rt) {
        int o = og * 32 + rt * 16 + l15;
        half8_t f;
#pragma unroll
        for (int j = 0; j < 8; ++j) {
          int q = q0 + j;
          float v = (q < 9) ? Wb[gi * 1152 + o * 9 + q]
                            : (q == 9 ? bb[gi * 128 + o] : 0.f);
          f[j] = (_Float16)v;
        }
        abk[gi - 1][rt] = f;
      }
#pragma unroll
    for (int rt = 0; rt < 2; ++rt) {
      float4_t au = __builtin_amdgcn_mfma_f32_16x16x32_f16(abk[0][rt], bbk, zero4, 0, 0, 0);
      float4_t ag = __builtin_amdgcn_mfma_f32_16x16x32_f16(abk[1][rt], bbk, zero4, 0, 0, 0);
#pragma unroll
      for (int r = 0; r < 4; ++r) {
        int row = og * 32 + rt * 16 + q4 * 4 + r;
        float uu = sigmoidf_(au[r]);
        float gg = tanhf_(ag[r]);
        hb_lds[row * 16 + l15] = (1.f - uu) * gg;
        hf_lds[row * 16 + l15] = cr[rt][r];
      }
    }
  }
  __syncthreads();

  // decoder
  if (tid < 192) {
    int i = tid >> 4, cc = tid & 15;
    const float* dwa = dec_w + (size_t)i * 512;
    const float* dwb = dwa + 256;
    float hd = dec_b[i];
    for (int e = 0; e < 128; ++e) {
      hd = fmaf(dwa[e] + dwb[e], hf_lds[e * 16 + cc], hd);
      hd = fmaf(dwa[128 + e] + dwb[128 + e], hb_lds[e * 16 + cc], hd);
    }
    hdec_lds[i * 16 + cc] = hd;
  }
  __syncthreads();
  if (tid < 192) {
    int o = tid >> 4, cc = tid & 15;
    float v = out_b[o];
#pragma unroll
    for (int i = 0; i < 12; ++i) v = fmaf(out_w[o * 12 + i], hdec_lds[i * 16 + cc], v);
    out[((size_t)(b * 12 + o)) * 512 + n0 + cc] = v;
  }
}

extern "C" void kernel_launch(void* const* d_in, const int* in_sizes, int n_in,
                              void* d_out, int out_size, void* d_ws, size_t ws_size,
                              hipStream_t stream) {
  (void)in_sizes; (void)n_in; (void)out_size; (void)ws_size;
  const float* x     = (const float*)d_in[0];
  const float* adj   = (const float*)d_in[1];
  const float* Wf    = (const float*)d_in[2];
  const float* Uf    = (const float*)d_in[3];
  const float* bf    = (const float*)d_in[4];
  const float* E1f   = (const float*)d_in[5];
  const float* E2f   = (const float*)d_in[6];
  const float* Wb    = (const float*)d_in[7];
  const float* bb    = (const float*)d_in[9];
  const float* E1b   = (const float*)d_in[10];
  const float* E2b   = (const float*)d_in[11];
  const float* dec_w = (const float*)d_in[12];
  const float* dec_b = (const float*)d_in[13];
  const float* out_w = (const float*)d_in[14];
  const float* out_b = (const float*)d_in[15];

  _Float16* h      = (_Float16*)d_ws;
  _Float16* adjT   = h;                       // 512*512
  _Float16* AfT    = h + 262144;              // 512*512
  _Float16* AbT    = h + 524288;              // 512*512
  _Float16* msg16  = h + 786432;              // 1024*512*16
  _Float16* msgb16 = msg16 + 8388608;         // 16*512*16

  prep_kernel<<<1152, 256, 0, stream>>>(E1f, E2f, E1b, E2b, adj, adjT, AfT, AbT);
  msg_kernel<<<256, 256, 0, stream>>>(x, adjT, AfT, AbT, msg16, msgb16);
  rec_kernel<<<512, 256, 0, stream>>>(msg16, msgb16, Wf, Uf, bf, Wb, bb,
                                      dec_w, dec_b, out_w, out_b, (float*)d_out);
}

// Round 4
// 214.655 us; speedup vs baseline: 14.9466x; 1.4280x over previous
//
#include <hip/hip_runtime.h>

// IBNModel: graph-coupled bidirectional GRU + decoder. All fp32 in/out.
// B=16, H=64, N=512, C=3, E=128, D=32, L_OUT=12, LAYERS=2.
//
//  K1 prep_kernel : softmax(relu(E1 E2^T)) -> fp16 transposed AfT/AbT;
//                   adj -> adjT fp16; Uf/Wf/bf -> fp16 MFMA-frag table ufrag;
//                   Wb/bb -> wbfrag. (frag tables: rec loads A-operands as
//                   plain 16B loads, zero per-step conversion VALU)
//  K2 msg_kernel  : MFMA GEMM, Mtile=48 (b,c for fixed t), Ntile=64, grid 512.
//                   Writes msg16[(t*16+b)][n][k16] (k0-2=x, k3-5=x@adj,
//                   k6-8=x@Af, k9=1, k10-15=0) via LDS-staged 32B stores.
//  K3 rec_kernel  : MFMA recurrence, 16 cols/block, 512 blocks (2/CU).
//                   Full 64-step msg slice in LDS; U/W/b frags persist in
//                   regs (fp16, from ufrag); c fp32 in regs; rcp-based
//                   sigmoid/tanh (no IEEE divide sequences).

typedef _Float16 half8_t __attribute__((ext_vector_type(8)));
typedef float float4_t __attribute__((ext_vector_type(4)));

__device__ __forceinline__ float sigmoidf_(float x) {
  return __builtin_amdgcn_rcpf(1.f + __expf(-x));
}
__device__ __forceinline__ float tanhf_(float x) {
  return fmaf(-2.f, __builtin_amdgcn_rcpf(__expf(2.f * x) + 1.f), 1.f);
}

// ---------------- K1: prep --------------------------------------------------
__global__ __launch_bounds__(256) void prep_kernel(
    const float* __restrict__ E1f, const float* __restrict__ E2f,
    const float* __restrict__ E1b, const float* __restrict__ E2b,
    const float* __restrict__ adj, const float* __restrict__ Wf,
    const float* __restrict__ Uf, const float* __restrict__ bf,
    const float* __restrict__ Wb, const float* __restrict__ bb,
    _Float16* __restrict__ adjT, _Float16* __restrict__ AfT,
    _Float16* __restrict__ AbT, _Float16* __restrict__ ufrag,
    _Float16* __restrict__ wbfrag) {
  int bid = blockIdx.x;
  int tid = threadIdx.x;
  if (bid >= 1272) {  // wbfrag: 16 regions (backward W|b frags, gates u,g)
    int r2 = bid - 1272;
    int gi = 1 + (r2 & 1);
    int rt = (r2 >> 1) & 1;
    int og = r2 >> 2;
    for (int e = tid; e < 512; e += 256) {
      int lane = e >> 3, j = e & 7;
      int o = og * 32 + rt * 16 + (lane & 15);
      int q = (lane >> 4) * 8 + j;
      float v = (q < 9) ? Wb[gi * 1152 + o * 9 + q]
                        : (q == 9 ? bb[gi * 128 + o] : 0.f);
      wbfrag[r2 * 512 + e] = (_Float16)v;
    }
    return;
  }
  if (bid >= 1152) {  // ufrag: 120 regions = ((og*2+rt)*3+gi)*5+kb
    int r = bid - 1152;
    int kb = r % 5;
    int gi = (r / 5) % 3;
    int rt = (r / 15) % 2;
    int og = r / 30;
    for (int e = tid; e < 512; e += 256) {
      int lane = e >> 3, j = e & 7;
      int o = og * 32 + rt * 16 + (lane & 15);
      int q4 = lane >> 4;
      float v;
      if (kb < 4) {
        v = Uf[gi * 16384 + o * 128 + kb * 32 + q4 * 8 + j];
      } else {
        int q = q4 * 8 + j;
        v = (q < 9) ? Wf[gi * 1152 + o * 9 + q]
                    : (q == 9 ? bf[gi * 128 + o] : 0.f);
      }
      ufrag[r * 512 + e] = (_Float16)v;
    }
    return;
  }
  if (bid >= 1024) {  // adj -> adjT fp16 (transpose)
    int base = (bid - 1024) * 4;
    for (int r = 0; r < 4; ++r) {
      int row = base + r;
      float v0 = adj[row * 512 + tid];
      float v1 = adj[row * 512 + tid + 256];
      adjT[(size_t)tid * 512 + row] = (_Float16)v0;
      adjT[(size_t)(tid + 256) * 512 + row] = (_Float16)v1;
    }
    return;
  }
  int which = bid >> 9;
  int row = bid & 511;
  const float* E1 = which ? E1b : E1f;
  const float* E2 = which ? E2b : E2f;
  _Float16* A = which ? AbT : AfT;
  __shared__ float e1s[32];
  __shared__ float red[256];
  if (tid < 32) e1s[tid] = E1[row * 32 + tid];
  __syncthreads();
  float s[2];
#pragma unroll
  for (int h = 0; h < 2; ++h) {
    int m = tid + h * 256;
    const float4* e2 = (const float4*)(E2 + m * 32);
    float acc = 0.f;
#pragma unroll
    for (int d4 = 0; d4 < 8; ++d4) {
      float4 v = e2[d4];
      acc = fmaf(v.x, e1s[d4 * 4 + 0], acc);
      acc = fmaf(v.y, e1s[d4 * 4 + 1], acc);
      acc = fmaf(v.z, e1s[d4 * 4 + 2], acc);
      acc = fmaf(v.w, e1s[d4 * 4 + 3], acc);
    }
    s[h] = fmaxf(acc, 0.f);
  }
  red[tid] = fmaxf(s[0], s[1]);
  __syncthreads();
  for (int off = 128; off > 0; off >>= 1) {
    if (tid < off) red[tid] = fmaxf(red[tid], red[tid + off]);
    __syncthreads();
  }
  float mx = red[0];
  __syncthreads();
  float e0 = __expf(s[0] - mx), e1v = __expf(s[1] - mx);
  red[tid] = e0 + e1v;
  __syncthreads();
  for (int off = 128; off > 0; off >>= 1) {
    if (tid < off) red[tid] += red[tid + off];
    __syncthreads();
  }
  float inv = __builtin_amdgcn_rcpf(red[0]);
  A[(size_t)tid * 512 + row] = (_Float16)(e0 * inv);
  A[(size_t)(tid + 256) * 512 + row] = (_Float16)(e1v * inv);
}

// ---------------- K2: message GEMM (MFMA) ----------------------------------
// grid 512 = t(64) x nc(8); 256 threads = 4 waves, 2 blocks/CU (80 KB LDS).
// Wave og owns n16 tile og. A = x[b][t][:][:] as [m=b*3+c][k=n], staged in
// LDS XOR-swizzled. B = adjT/AfT fp16 [n][k] 16B frags straight from L2.
__global__ __launch_bounds__(256, 2) void msg_kernel(
    const float* __restrict__ x, const _Float16* __restrict__ adjT,
    const _Float16* __restrict__ AfT, const _Float16* __restrict__ AbT,
    _Float16* __restrict__ msg16, _Float16* __restrict__ msgb16) {
  __shared__ __align__(16) _Float16 Alds[48 * 512];     // 48 KB
  __shared__ __align__(16) _Float16 Sst[16 * 64 * 16];  // 32 KB
  int tid = threadIdx.x;
  int t = blockIdx.x >> 3;
  int n0g = (blockIdx.x & 7) * 64;
  int lane = tid & 63, og = tid >> 6;
  int l15 = lane & 15, q4 = lane >> 4, q0 = q4 * 8;
  bool is63 = (t == 63);

  // stage x -> Alds (coalesced 256B runs per 16-thread group)
  {
    int b = tid >> 4, li = tid & 15;
    const float4* xb = (const float4*)(x + (size_t)(b * 64 + t) * 1536);
#pragma unroll
    for (int k = 0; k < 24; ++k) {
      float4 v = xb[k * 16 + li];
      int j0 = (k * 16 + li) * 4;
#pragma unroll
      for (int e = 0; e < 4; ++e) {
        int j = j0 + e;
        int n = (j * 21846) >> 16;  // exact j/3 for j<2048
        int c = j - n * 3;
        int m = b * 3 + c;
        float val = (e == 0) ? v.x : (e == 1) ? v.y : (e == 2) ? v.z : v.w;
        Alds[m * 512 + ((((n >> 3) ^ (m & 7)) << 3) | (n & 7))] = (_Float16)val;
      }
    }
  }
  __syncthreads();

  const float4_t zero4 = {0.f, 0.f, 0.f, 0.f};
  float4_t acc[3][2], accb[3];
#pragma unroll
  for (int mt = 0; mt < 3; ++mt) { acc[mt][0] = zero4; acc[mt][1] = zero4; accb[mt] = zero4; }

  int n = n0g + og * 16 + l15;
  for (int kb = 0; kb < 16; ++kb) {
    half8_t afr[3];
#pragma unroll
    for (int mt = 0; mt < 3; ++mt) {
      int m = mt * 16 + l15;
      afr[mt] = *(const half8_t*)&Alds[m * 512 + ((((kb * 4 + q4) ^ (m & 7)) << 3))];
    }
    half8_t b0 = *(const half8_t*)&adjT[(size_t)n * 512 + kb * 32 + q0];
    half8_t b1 = *(const half8_t*)&AfT[(size_t)n * 512 + kb * 32 + q0];
#pragma unroll
    for (int mt = 0; mt < 3; ++mt) {
      acc[mt][0] = __builtin_amdgcn_mfma_f32_16x16x32_f16(afr[mt], b0, acc[mt][0], 0, 0, 0);
      acc[mt][1] = __builtin_amdgcn_mfma_f32_16x16x32_f16(afr[mt], b1, acc[mt][1], 0, 0, 0);
    }
    if (is63) {
      half8_t b2 = *(const half8_t*)&AbT[(size_t)n * 512 + kb * 32 + q0];
#pragma unroll
      for (int mt = 0; mt < 3; ++mt)
        accb[mt] = __builtin_amdgcn_mfma_f32_16x16x32_f16(afr[mt], b2, accb[mt], 0, 0, 0);
    }
  }

  // stage results: Sst[tb][nl][k16]
  for (int i = tid; i < 1024; i += 256) {
    int tb = i >> 6, nl = i & 63;
    int nn = n0g + nl;
    _Float16* row = &Sst[(tb * 64 + nl) * 16];
#pragma unroll
    for (int c = 0; c < 3; ++c) {
      int m = tb * 3 + c;
      row[c] = Alds[m * 512 + ((((nn >> 3) ^ (m & 7)) << 3) | (nn & 7))];
    }
    row[9] = (_Float16)1.f;
#pragma unroll
    for (int kz = 10; kz < 16; ++kz) row[kz] = (_Float16)0.f;
  }
#pragma unroll
  for (int mt = 0; mt < 3; ++mt)
#pragma unroll
    for (int r = 0; r < 4; ++r) {
      int m = mt * 16 + q4 * 4 + r;
      int tb = (m * 21846) >> 16;
      int c = m - tb * 3;
      _Float16* row = &Sst[(tb * 64 + og * 16 + l15) * 16];
      row[3 + c] = (_Float16)acc[mt][0][r];
      row[6 + c] = (_Float16)acc[mt][1][r];
    }
  __syncthreads();
  // coalesced 32B-per-row write-out
  for (int i = tid; i < 1024; i += 256) {
    int tb = i >> 6, nl = i & 63;
    uint4* dst = (uint4*)&msg16[((size_t)(t * 16 + tb) * 512 + n0g + nl) * 16];
    const uint4* s = (const uint4*)&Sst[(tb * 64 + nl) * 16];
    dst[0] = s[0];
    dst[1] = s[1];
  }
  if (is63) {
    __syncthreads();
#pragma unroll
    for (int mt = 0; mt < 3; ++mt)
#pragma unroll
      for (int r = 0; r < 4; ++r) {
        int m = mt * 16 + q4 * 4 + r;
        int tb = (m * 21846) >> 16;
        int c = m - tb * 3;
        Sst[(tb * 64 + og * 16 + l15) * 16 + 6 + c] = (_Float16)accb[mt][r];
      }
    __syncthreads();
    for (int i = tid; i < 1024; i += 256) {
      int tb = i >> 6, nl = i & 63;
      uint4* dst = (uint4*)&msgb16[((size_t)tb * 512 + n0g + nl) * 16];
      const uint4* s = (const uint4*)&Sst[(tb * 64 + nl) * 16];
      dst[0] = s[0];
      dst[1] = s[1];
    }
  }
}

// ---------------- K3: MFMA recurrence + backward + decoder ------------------
// grid 512 = b(16) x ntile(32), 16 cols; 256 threads = 4 waves, 2 blocks/CU.
// Wave og owns rows [og*32, og*32+32). A-frags preloaded fp16 from ufrag
// (30 x 16B plain loads -> 120 VGPRs, budget 256 via waves_per_eu(2,2)).
__global__ __launch_bounds__(256, 2) __attribute__((amdgpu_waves_per_eu(2, 2)))
void rec_kernel(
    const _Float16* __restrict__ msg16, const _Float16* __restrict__ msgb16,
    const _Float16* __restrict__ ufrag, const _Float16* __restrict__ wbfrag,
    const float* __restrict__ dec_w, const float* __restrict__ dec_b,
    const float* __restrict__ out_w, const float* __restrict__ out_b,
    float* __restrict__ out) {
  __shared__ __align__(16) _Float16 Bmsg[64 * 16 * 16];  // 32 KB (swizzled)
  __shared__ __align__(16) _Float16 Cbuf[4 * 64 * 8];    // 4 KB
  __shared__ __align__(16) _Float16 Gbuf[4 * 64 * 8];    // 4 KB
  __shared__ float hf_lds[128 * 16];
  __shared__ float hb_lds[128 * 16];
  __shared__ float hdec_lds[12 * 16];
  int tid = threadIdx.x, bid = blockIdx.x;
  int b = bid >> 5;
  int n0 = (bid & 31) * 16;
  int lane = tid & 63, og = tid >> 6;
  int l15 = lane & 15, q4 = lane >> 4;

  // persistent A frags: plain 16B loads, no conversion
  half8_t afrag[3][2][5];
#pragma unroll
  for (int gi = 0; gi < 3; ++gi)
#pragma unroll
    for (int rt = 0; rt < 2; ++rt)
#pragma unroll
      for (int kb = 0; kb < 5; ++kb)
        afrag[gi][rt][kb] = *(const half8_t*)
            &ufrag[(size_t)((((og * 2 + rt) * 3 + gi) * 5 + kb) * 512) + lane * 8];

  // preload 64-step msg slice, swizzling the two 16B halves of each n-row
  {
    const uint4* src = (const uint4*)msg16;
    uint4* dst = (uint4*)Bmsg;
    for (int f = tid; f < 2048; f += 256) {
      int t = f >> 5, off = f & 31;
      int nn = off >> 1, h = off & 1;
      dst[t * 32 + nn * 2 + (h ^ (nn & 1))] =
          src[((size_t)(t * 16 + b) * 512 + n0) * 2 + off];
    }
  }
  {
    uint4 z; z.x = z.y = z.z = z.w = 0;
    ((uint4*)Cbuf)[tid] = z;
  }
  float cr[2][4];
#pragma unroll
  for (int rt = 0; rt < 2; ++rt)
#pragma unroll
    for (int r = 0; r < 4; ++r) cr[rt][r] = 0.f;
  __syncthreads();

  const float4_t zero4 = {0.f, 0.f, 0.f, 0.f};
  union H4U { _Float16 h[4]; unsigned long long u; };
  int bm_off = l15 * 16 + (((q4 & 1) ^ (l15 & 1)) << 3);

  for (int t = 0; t < 64; ++t) {
    half8_t bmsg = *(const half8_t*)&Bmsg[t * 256 + bm_off];
    half8_t cf[4];
#pragma unroll
    for (int kb = 0; kb < 4; ++kb)
      cf[kb] = *(const half8_t*)&Cbuf[(kb * 64 + lane) * 8];

    float4_t accr[2], accu[2];
    accr[0] = accr[1] = accu[0] = accu[1] = zero4;
#pragma unroll
    for (int kb = 0; kb < 4; ++kb)
#pragma unroll
      for (int rt = 0; rt < 2; ++rt) {
        accr[rt] = __builtin_amdgcn_mfma_f32_16x16x32_f16(afrag[0][rt][kb], cf[kb], accr[rt], 0, 0, 0);
        accu[rt] = __builtin_amdgcn_mfma_f32_16x16x32_f16(afrag[1][rt][kb], cf[kb], accu[rt], 0, 0, 0);
      }
#pragma unroll
    for (int rt = 0; rt < 2; ++rt) {
      accr[rt] = __builtin_amdgcn_mfma_f32_16x16x32_f16(afrag[0][rt][4], bmsg, accr[rt], 0, 0, 0);
      accu[rt] = __builtin_amdgcn_mfma_f32_16x16x32_f16(afrag[1][rt][4], bmsg, accu[rt], 0, 0, 0);
    }
#pragma unroll
    for (int rt = 0; rt < 2; ++rt) {
      H4U v;
#pragma unroll
      for (int r = 0; r < 4; ++r)
        v.h[r] = (_Float16)(sigmoidf_(accr[rt][r]) * cr[rt][r]);
      int lane_t = (rt * 2 + (q4 >> 1)) * 16 + l15;
      *(unsigned long long*)&Gbuf[(og * 64 + lane_t) * 8 + (q4 & 1) * 4] = v.u;
    }
    __syncthreads();  // rc visible; Cbuf reads done

    half8_t gf[4];
#pragma unroll
    for (int kb = 0; kb < 4; ++kb)
      gf[kb] = *(const half8_t*)&Gbuf[(kb * 64 + lane) * 8];
    float4_t accg[2];
#pragma unroll
    for (int rt = 0; rt < 2; ++rt) {
      float4_t a = zero4;
#pragma unroll
      for (int kb = 0; kb < 4; ++kb)
        a = __builtin_amdgcn_mfma_f32_16x16x32_f16(afrag[2][rt][kb], gf[kb], a, 0, 0, 0);
      a = __builtin_amdgcn_mfma_f32_16x16x32_f16(afrag[2][rt][4], bmsg, a, 0, 0, 0);
      accg[rt] = a;
    }
#pragma unroll
    for (int rt = 0; rt < 2; ++rt) {
      H4U v;
#pragma unroll
      for (int r = 0; r < 4; ++r) {
        float uu = sigmoidf_(accu[rt][r]);
        float gg = tanhf_(accg[rt][r]);
        float cn = fmaf(uu, cr[rt][r] - gg, gg);  // u*c + (1-u)*g
        cr[rt][r] = cn;
        v.h[r] = (_Float16)cn;
      }
      int lane_t = (rt * 2 + (q4 >> 1)) * 16 + l15;
      *(unsigned long long*)&Cbuf[(og * 64 + lane_t) * 8 + (q4 & 1) * 4] = v.u;
    }
    __syncthreads();  // c_{t+1} visible; Gbuf reads done
  }

  // backward cell at t=63, c0=0: h_back = (1-sig(pre_u))*tanh(pre_g)
  {
    half8_t bbk = *(const half8_t*)
        &msgb16[((size_t)b * 512 + n0 + l15) * 16 + (q4 & 1) * 8];
#pragma unroll
    for (int rt = 0; rt < 2; ++rt) {
      half8_t au_f = *(const half8_t*)&wbfrag[(size_t)(((og * 2 + rt) * 2 + 0) * 512) + lane * 8];
      half8_t ag_f = *(const half8_t*)&wbfrag[(size_t)(((og * 2 + rt) * 2 + 1) * 512) + lane * 8];
      float4_t au = __builtin_amdgcn_mfma_f32_16x16x32_f16(au_f, bbk, zero4, 0, 0, 0);
      float4_t ag = __builtin_amdgcn_mfma_f32_16x16x32_f16(ag_f, bbk, zero4, 0, 0, 0);
#pragma unroll
      for (int r = 0; r < 4; ++r) {
        int row = og * 32 + rt * 16 + q4 * 4 + r;
        float uu = sigmoidf_(au[r]);
        float gg = tanhf_(ag[r]);
        hb_lds[row * 16 + l15] = (1.f - uu) * gg;
        hf_lds[row * 16 + l15] = cr[rt][r];
      }
    }
  }
  __syncthreads();

  // decoder
  if (tid < 192) {
    int i = tid >> 4, cc = tid & 15;
    const float* dwa = dec_w + (size_t)i * 512;
    const float* dwb = dwa + 256;
    float hd = dec_b[i];
    for (int e = 0; e < 128; ++e) {
      hd = fmaf(dwa[e] + dwb[e], hf_lds[e * 16 + cc], hd);
      hd = fmaf(dwa[128 + e] + dwb[128 + e], hb_lds[e * 16 + cc], hd);
    }
    hdec_lds[i * 16 + cc] = hd;
  }
  __syncthreads();
  if (tid < 192) {
    int o = tid >> 4, cc = tid & 15;
    float v = out_b[o];
#pragma unroll
    for (int i = 0; i < 12; ++i) v = fmaf(out_w[o * 12 + i], hdec_lds[i * 16 + cc], v);
    out[((size_t)(b * 12 + o)) * 512 + n0 + cc] = v;
  }
}

extern "C" void kernel_launch(void* const* d_in, const int* in_sizes, int n_in,
                              void* d_out, int out_size, void* d_ws, size_t ws_size,
                              hipStream_t stream) {
  (void)in_sizes; (void)n_in; (void)out_size; (void)ws_size;
  const float* x     = (const float*)d_in[0];
  const float* adj   = (const float*)d_in[1];
  const float* Wf    = (const float*)d_in[2];
  const float* Uf    = (const float*)d_in[3];
  const float* bf    = (const float*)d_in[4];
  const float* E1f   = (const float*)d_in[5];
  const float* E2f   = (const float*)d_in[6];
  const float* Wb    = (const float*)d_in[7];
  const float* bb    = (const float*)d_in[9];
  const float* E1b   = (const float*)d_in[10];
  const float* E2b   = (const float*)d_in[11];
  const float* dec_w = (const float*)d_in[12];
  const float* dec_b = (const float*)d_in[13];
  const float* out_w = (const float*)d_in[14];
  const float* out_b = (const float*)d_in[15];

  _Float16* h      = (_Float16*)d_ws;
  _Float16* adjT   = h;                       // 262144
  _Float16* AfT    = h + 262144;              // 262144
  _Float16* AbT    = h + 524288;              // 262144
  _Float16* msg16  = h + 786432;              // 8388608
  _Float16* msgb16 = h + 9175040;             // 131072
  _Float16* ufrag  = h + 9306112;             // 61440
  _Float16* wbfrag = h + 9367552;             // 8192

  prep_kernel<<<1288, 256, 0, stream>>>(E1f, E2f, E1b, E2b, adj, Wf, Uf, bf,
                                        Wb, bb, adjT, AfT, AbT, ufrag, wbfrag);
  msg_kernel<<<512, 256, 0, stream>>>(x, adjT, AfT, AbT, msg16, msgb16);
  rec_kernel<<<512, 256, 0, stream>>>(msg16, msgb16, ufrag, wbfrag,
                                      dec_w, dec_b, out_w, out_b, (float*)d_out);
}